// Round 1
// baseline (358.262 us; speedup 1.0000x reference)
//
#include <hip/hip_runtime.h>

typedef __attribute__((ext_vector_type(8))) short bf16x8;
typedef __attribute__((ext_vector_type(4))) float f32x4;

__device__ inline unsigned short f2bf(float f) {
  unsigned int x;
  __builtin_memcpy(&x, &f, 4);
  x += 0x7fffu + ((x >> 16) & 1u);   // RNE round to bf16
  return (unsigned short)(x >> 16);
}

// ---------- f32 -> bf16 convert, float4-vectorized ----------
__global__ __launch_bounds__(256) void conv_kernel(const float4* __restrict__ in,
                                                   ushort4* __restrict__ out, int n4) {
  int stride = gridDim.x * blockDim.x;
  for (int i = blockIdx.x * blockDim.x + threadIdx.x; i < n4; i += stride) {
    float4 v = in[i];
    ushort4 o;
    o.x = f2bf(v.x); o.y = f2bf(v.y); o.z = f2bf(v.z); o.w = f2bf(v.w);
    out[i] = o;
  }
}

// ---------- bf16 NT GEMM: out[m][n] = sum_k A[m][k] * Bm[n][k], 128x128 tile ----------
// MODE 0: N=2048 stacked; col<1024 -> alpha=sigmoid(acc+bias0[col]) fp32
//                         col>=1024 -> Bu = acc + bias1[col-1024] fp32
// MODE 1: N=1024; out0[idx] = acc + bias0[col] * bias1[idx]   (y = hsC^T + D*u)
#define LDP 72

template <int MODE>
__global__ __launch_bounds__(256) void gemm_nt(const unsigned short* __restrict__ A,
                                               const unsigned short* __restrict__ Bm,
                                               int K,
                                               const float* __restrict__ bias0,
                                               const float* __restrict__ bias1,
                                               float* __restrict__ out0,
                                               float* __restrict__ out1) {
  __shared__ __align__(16) unsigned short sA[128 * LDP];
  __shared__ __align__(16) unsigned short sB[128 * LDP];
  const int tid = threadIdx.x;
  const int lane = tid & 63;
  const int wave = tid >> 6;
  const int wr = wave >> 1, wc = wave & 1;
  const int l15 = lane & 15, lhi = lane >> 4;
  const int m0 = blockIdx.y * 128, n0 = blockIdx.x * 128;

  f32x4 acc[4][4] = {};

  for (int ks = 0; ks < K; ks += 64) {
    __syncthreads();
#pragma unroll
    for (int it = 0; it < 4; ++it) {
      int cid = it * 256 + tid;
      int row = cid >> 3, kc = (cid & 7) << 3;
      *reinterpret_cast<bf16x8*>(&sA[row * LDP + kc]) =
          *reinterpret_cast<const bf16x8*>(&A[(size_t)(m0 + row) * K + ks + kc]);
      *reinterpret_cast<bf16x8*>(&sB[row * LDP + kc]) =
          *reinterpret_cast<const bf16x8*>(&Bm[(size_t)(n0 + row) * K + ks + kc]);
    }
    __syncthreads();
#pragma unroll
    for (int kk = 0; kk < 2; ++kk) {
      bf16x8 af[4], bg[4];
#pragma unroll
      for (int i = 0; i < 4; ++i)
        af[i] = *reinterpret_cast<const bf16x8*>(
            &sA[(wr * 64 + i * 16 + l15) * LDP + kk * 32 + lhi * 8]);
#pragma unroll
      for (int j = 0; j < 4; ++j)
        bg[j] = *reinterpret_cast<const bf16x8*>(
            &sB[(wc * 64 + j * 16 + l15) * LDP + kk * 32 + lhi * 8]);
#pragma unroll
      for (int i = 0; i < 4; ++i)
#pragma unroll
        for (int j = 0; j < 4; ++j)
          acc[i][j] = __builtin_amdgcn_mfma_f32_16x16x32_bf16(af[i], bg[j], acc[i][j], 0, 0, 0);
    }
  }

#pragma unroll
  for (int i = 0; i < 4; ++i) {
#pragma unroll
    for (int j = 0; j < 4; ++j) {
      int gcol = n0 + wc * 64 + j * 16 + l15;
#pragma unroll
      for (int r = 0; r < 4; ++r) {
        int grow = m0 + wr * 64 + i * 16 + lhi * 4 + r;
        float v = acc[i][j][r];
        if (MODE == 0) {
          if (gcol < 1024) {
            float z = v + bias0[gcol];
            out0[(size_t)grow * 1024 + gcol] = 1.0f / (1.0f + __expf(-z));
          } else {
            int c = gcol - 1024;
            out1[(size_t)grow * 1024 + c] = v + bias1[c];
          }
        } else {
          size_t idx = (size_t)grow * 1024 + gcol;
          out0[idx] = v + bias0[gcol] * bias1[idx];
        }
      }
    }
  }
}

// ---------- sequential scan over T, one thread per (b, n) ----------
// grid = B * (n/64) = 128 blocks, 64 threads. Coalesced over n.
__global__ __launch_bounds__(64) void scan_kernel(const float* __restrict__ alpha,
                                                  const float* __restrict__ Bu,
                                                  unsigned short* __restrict__ hs) {
  int b = blockIdx.x >> 4;                       // n/64 = 16
  int n0 = ((blockIdx.x & 15) << 6) | threadIdx.x;
  size_t base = (size_t)b * 2048 * 1024 + n0;
  float h = 0.0f;
  for (int t = 0; t < 2048; t += 8) {
    float a[8], bb[8];
#pragma unroll
    for (int q = 0; q < 8; ++q) {
      size_t idx = base + (size_t)(t + q) * 1024;
      a[q] = alpha[idx];
      bb[q] = Bu[idx];
    }
#pragma unroll
    for (int q = 0; q < 8; ++q) {
      h = __builtin_fmaf(a[q], h, bb[q]);
      hs[base + (size_t)(t + q) * 1024] = f2bf(h);
    }
  }
}

extern "C" void kernel_launch(void* const* d_in, const int* in_sizes, int n_in,
                              void* d_out, int out_size, void* d_ws, size_t ws_size,
                              hipStream_t stream) {
  const float* u   = (const float*)d_in[0];
  const float* Waw = (const float*)d_in[1];
  const float* Wab = (const float*)d_in[2];
  const float* WBw = (const float*)d_in[3];
  const float* WBb = (const float*)d_in[4];
  const float* Cw  = (const float*)d_in[5];
  const float* Dv  = (const float*)d_in[6];
  float* y = (float*)d_out;

  const int T = 2048, DM = 1024, NS = 1024, Bb = 8;
  const size_t M = (size_t)Bb * T;  // 16384

  char* ws = (char*)d_ws;
  unsigned short* u_bf = (unsigned short*)(ws);                  // 32 MB
  unsigned short* W_bf = (unsigned short*)(ws + (32ull << 20));  // 4 MB (W_alpha ; W_B stacked)
  unsigned short* C_bf = (unsigned short*)(ws + (36ull << 20));  // 2 MB
  float* alpha         = (float*)(ws + (38ull << 20));           // 64 MB
  float* Bu            = (float*)(ws + (102ull << 20));          // 64 MB
  unsigned short* hs   = (unsigned short*)(ws + (166ull << 20)); // 32 MB  (total 198 MB)

  // converts
  conv_kernel<<<2048, 256, 0, stream>>>((const float4*)u, (ushort4*)u_bf, (int)(M * DM / 4));
  conv_kernel<<<512, 256, 0, stream>>>((const float4*)Waw, (ushort4*)W_bf, NS * DM / 4);
  conv_kernel<<<512, 256, 0, stream>>>((const float4*)WBw, (ushort4*)(W_bf + (size_t)NS * DM),
                                       NS * DM / 4);
  conv_kernel<<<512, 256, 0, stream>>>((const float4*)Cw, (ushort4*)C_bf, NS * DM / 4);

  // GEMM1: [M,2048] = u @ [W_alpha;W_B]^T, fused sigmoid/bias epilogue
  gemm_nt<0><<<dim3(2048 / 128, (int)(M / 128)), 256, 0, stream>>>(u_bf, W_bf, DM, Wab, WBb,
                                                                   alpha, Bu);
  // scan over T
  scan_kernel<<<Bb * (NS / 64), 64, 0, stream>>>(alpha, Bu, hs);
  // GEMM3: y = hs @ C^T + D*u
  gemm_nt<1><<<dim3(1024 / 128, (int)(M / 128)), 256, 0, stream>>>(hs, C_bf, NS, Dv, u, y,
                                                                   nullptr);
}

// Round 3
// 283.153 us; speedup vs baseline: 1.2653x; 1.2653x over previous
//
#include <hip/hip_runtime.h>

typedef __attribute__((ext_vector_type(8))) short bf16x8;
typedef __attribute__((ext_vector_type(4))) float f32x4;

__device__ __forceinline__ unsigned short f2bf(float f) {
  unsigned int x;
  __builtin_memcpy(&x, &f, 4);
  x += 0x7fffu + ((x >> 16) & 1u);   // RNE round to bf16
  return (unsigned short)(x >> 16);
}

__device__ __forceinline__ float bf2f(unsigned short s) {
  unsigned int x = ((unsigned int)s) << 16;
  float f;
  __builtin_memcpy(&f, &x, 4);
  return f;
}

// async global->LDS, 16B per lane, wave-uniform LDS base
__device__ __forceinline__ void gl_lds16(const unsigned short* gsrc, unsigned short* ldst) {
  __builtin_amdgcn_global_load_lds(
      (const __attribute__((address_space(1))) void*)gsrc,
      (__attribute__((address_space(3))) void*)ldst, 16, 0, 0);
}

// ---------- f32 -> bf16 convert, float4-vectorized ----------
__global__ __launch_bounds__(256) void conv_kernel(const float4* __restrict__ in,
                                                   ushort4* __restrict__ out, int n4) {
  int stride = gridDim.x * blockDim.x;
  for (int i = blockIdx.x * blockDim.x + threadIdx.x; i < n4; i += stride) {
    float4 v = in[i];
    ushort4 o;
    o.x = f2bf(v.x); o.y = f2bf(v.y); o.z = f2bf(v.z); o.w = f2bf(v.w);
    out[i] = o;
  }
}

// ---------- bf16 NT GEMM, m97 structure: 128x128 tile, BK=64, global_load_lds ----------
// out[m][n] = sum_k A[m][k] * Bm[n][k]
// MODE 0 (N=2048 stacked): col<1024 -> alpha = sigmoid(acc+bias0[col])  (fp32)
//                          col>=1024 -> Bu_bf = bf16(acc + bias1[col-1024])
// MODE 1 (N=1024): out0[idx] = acc + bias0[col] * bias1[idx]   (y = hs C^T + D*u)
template <int MODE>
__global__ __launch_bounds__(256) void gemm_nt(const unsigned short* __restrict__ A,
                                               const unsigned short* __restrict__ Bm,
                                               int K,
                                               const float* __restrict__ bias0,
                                               const float* __restrict__ bias1,
                                               float* __restrict__ out0,
                                               unsigned short* __restrict__ out1b) {
  __shared__ __align__(16) unsigned short sA[128 * 64];
  __shared__ __align__(16) unsigned short sB[128 * 64];
  const int tid = threadIdx.x;
  const int lane = tid & 63;
  const int wave = tid >> 6;
  const int wr = wave >> 1, wc = wave & 1;
  const int l15 = lane & 15, lhi = lane >> 4;
  const int rl = lane >> 3, kc = (lane & 7) << 3;   // staging: 8 lanes/row, 8 bf16/lane
  const int m0 = blockIdx.y * 128, n0 = blockIdx.x * 128;

  f32x4 acc[4][4] = {};

  for (int ks = 0; ks < K; ks += 64) {
    __syncthreads();   // previous tile's ds_reads done before overwrite
#pragma unroll
    for (int it = 0; it < 4; ++it) {
      int widx = wave * 4 + it;              // 16 chunks of 8 rows each
      gl_lds16(&A[(size_t)(m0 + widx * 8 + rl) * K + ks + kc], &sA[widx * 512]);
      gl_lds16(&Bm[(size_t)(n0 + widx * 8 + rl) * K + ks + kc], &sB[widx * 512]);
    }
    __syncthreads();   // compiler drains vmcnt before barrier
#pragma unroll
    for (int kk = 0; kk < 2; ++kk) {
      bf16x8 af[4], bg[4];
#pragma unroll
      for (int i = 0; i < 4; ++i)
        af[i] = *reinterpret_cast<const bf16x8*>(
            &sA[(wr * 64 + i * 16 + l15) * 64 + kk * 32 + lhi * 8]);
#pragma unroll
      for (int j = 0; j < 4; ++j)
        bg[j] = *reinterpret_cast<const bf16x8*>(
            &sB[(wc * 64 + j * 16 + l15) * 64 + kk * 32 + lhi * 8]);
#pragma unroll
      for (int i = 0; i < 4; ++i)
#pragma unroll
        for (int j = 0; j < 4; ++j)
          acc[i][j] = __builtin_amdgcn_mfma_f32_16x16x32_bf16(af[i], bg[j], acc[i][j], 0, 0, 0);
    }
  }

#pragma unroll
  for (int i = 0; i < 4; ++i) {
#pragma unroll
    for (int j = 0; j < 4; ++j) {
      int gcol = n0 + wc * 64 + j * 16 + l15;
#pragma unroll
      for (int r = 0; r < 4; ++r) {
        int grow = m0 + wr * 64 + i * 16 + lhi * 4 + r;
        float v = acc[i][j][r];
        if (MODE == 0) {
          if (gcol < 1024) {
            float z = v + bias0[gcol];
            out0[(size_t)grow * 1024 + gcol] = 1.0f / (1.0f + __expf(-z));
          } else {
            int c = gcol - 1024;
            out1b[(size_t)grow * 1024 + c] = f2bf(v + bias1[c]);
          }
        } else {
          size_t idx = (size_t)grow * 1024 + gcol;
          out0[idx] = v + bias0[gcol] * bias1[idx];
        }
      }
    }
  }
}

// ---------- chunked scan, pass 1: per-chunk (P = prod a, S = local scan end) ----------
// grid: 8 b * 16 chunks * 4 ngroups = 512 blocks x 256 thr; chunk length 128
__global__ __launch_bounds__(256) void scan_stats(const float* __restrict__ alpha,
                                                  const unsigned short* __restrict__ Bu,
                                                  float* __restrict__ P,
                                                  float* __restrict__ S) {
  int b = blockIdx.x >> 6;
  int c = (blockIdx.x >> 2) & 15;
  int n = ((blockIdx.x & 3) << 8) | threadIdx.x;
  int bn = (b << 10) | n;
  size_t base = ((size_t)b * 2048 + c * 128) * 1024 + n;
  float h = 0.0f, p = 1.0f;
  for (int t = 0; t < 128; t += 8) {
    float a[8], bb[8];
#pragma unroll
    for (int q = 0; q < 8; ++q) {
      size_t idx = base + (size_t)(t + q) * 1024;
      a[q] = alpha[idx];
      bb[q] = bf2f(Bu[idx]);
    }
#pragma unroll
    for (int q = 0; q < 8; ++q) {
      h = __builtin_fmaf(a[q], h, bb[q]);
      p *= a[q];
    }
  }
  P[c * 8192 + bn] = p;
  S[c * 8192 + bn] = h;
}

// ---------- chunked scan, pass 2: compose carry-in, recompute, emit hs bf16 ----------
__global__ __launch_bounds__(256) void scan_apply(const float* __restrict__ alpha,
                                                  const unsigned short* __restrict__ Bu,
                                                  const float* __restrict__ P,
                                                  const float* __restrict__ S,
                                                  unsigned short* __restrict__ hs) {
  int b = blockIdx.x >> 6;
  int c = (blockIdx.x >> 2) & 15;
  int n = ((blockIdx.x & 3) << 8) | threadIdx.x;
  int bn = (b << 10) | n;
  size_t base = ((size_t)b * 2048 + c * 128) * 1024 + n;
  float h = 0.0f;                       // carry into chunk c: compose chunks 0..c-1
  for (int j = 0; j < c; ++j) h = S[j * 8192 + bn] + P[j * 8192 + bn] * h;
  for (int t = 0; t < 128; t += 8) {
    float a[8], bb[8];
#pragma unroll
    for (int q = 0; q < 8; ++q) {
      size_t idx = base + (size_t)(t + q) * 1024;
      a[q] = alpha[idx];
      bb[q] = bf2f(Bu[idx]);
    }
#pragma unroll
    for (int q = 0; q < 8; ++q) {
      h = __builtin_fmaf(a[q], h, bb[q]);
      hs[base + (size_t)(t + q) * 1024] = f2bf(h);
    }
  }
}

extern "C" void kernel_launch(void* const* d_in, const int* in_sizes, int n_in,
                              void* d_out, int out_size, void* d_ws, size_t ws_size,
                              hipStream_t stream) {
  const float* u   = (const float*)d_in[0];
  const float* Waw = (const float*)d_in[1];
  const float* Wab = (const float*)d_in[2];
  const float* WBw = (const float*)d_in[3];
  const float* WBb = (const float*)d_in[4];
  const float* Cw  = (const float*)d_in[5];
  const float* Dv  = (const float*)d_in[6];
  float* y = (float*)d_out;

  const int DM = 1024, NS = 1024;
  const size_t M = 16384;  // B*T

  // Workspace map (no overlaps — round-2 bug was Bu_bf taking 32MB, not 16):
  //   u_bf  [  0, 32)MB  16384*1024*2
  //   W_bf  [ 32, 36)MB   2048*1024*2
  //   C_bf  [ 36, 38)MB   1024*1024*2
  //   alpha [ 38,102)MB  16384*1024*4
  //   Bu_bf [102,134)MB  16384*1024*2
  //   hs    [134,166)MB  16384*1024*2
  //   Pc    [166,166.5)MB, Sc [167,167.5)MB
  char* ws = (char*)d_ws;
  unsigned short* u_bf  = (unsigned short*)(ws);
  unsigned short* W_bf  = (unsigned short*)(ws + (32ull << 20));
  unsigned short* C_bf  = (unsigned short*)(ws + (36ull << 20));
  float*          alpha = (float*)(ws + (38ull << 20));
  unsigned short* Bu_bf = (unsigned short*)(ws + (102ull << 20));
  unsigned short* hs    = (unsigned short*)(ws + (134ull << 20));
  float*          Pc    = (float*)(ws + (166ull << 20));
  float*          Sc    = (float*)(ws + (167ull << 20));

  // converts
  conv_kernel<<<2048, 256, 0, stream>>>((const float4*)u, (ushort4*)u_bf, (int)(M * DM / 4));
  conv_kernel<<<512, 256, 0, stream>>>((const float4*)Waw, (ushort4*)W_bf, NS * DM / 4);
  conv_kernel<<<512, 256, 0, stream>>>((const float4*)WBw, (ushort4*)(W_bf + (size_t)NS * DM),
                                       NS * DM / 4);
  conv_kernel<<<512, 256, 0, stream>>>((const float4*)Cw, (ushort4*)C_bf, NS * DM / 4);

  // GEMM1: [M,2048] = u @ [W_alpha;W_B]^T, fused sigmoid / bf16-Bu epilogue
  gemm_nt<0><<<dim3(16, 128), 256, 0, stream>>>(u_bf, W_bf, DM, Wab, WBb, alpha, Bu_bf);
  // scan: per-chunk stats, then compose+apply
  scan_stats<<<512, 256, 0, stream>>>(alpha, Bu_bf, Pc, Sc);
  scan_apply<<<512, 256, 0, stream>>>(alpha, Bu_bf, Pc, Sc, hs);
  // GEMM3: y = hs @ C^T + D*u
  gemm_nt<1><<<dim3(8, 128), 256, 0, stream>>>(hs, C_bf, NS, Dv, u, y, nullptr);
}

// Round 4
// 206.901 us; speedup vs baseline: 1.7316x; 1.3685x over previous
//
#include <hip/hip_runtime.h>

typedef __attribute__((ext_vector_type(8))) short bf16x8;
typedef __attribute__((ext_vector_type(4))) float f32x4;

#define BAR() asm volatile("s_barrier" ::: "memory")
#define WAITV(N) asm volatile("s_waitcnt vmcnt(" #N ")" ::: "memory")

__device__ __forceinline__ unsigned short f2bf(float f) {
  unsigned int x;
  __builtin_memcpy(&x, &f, 4);
  x += 0x7fffu + ((x >> 16) & 1u);   // RNE round to bf16
  return (unsigned short)(x >> 16);
}

__device__ __forceinline__ float bf2f(unsigned short s) {
  unsigned int x = ((unsigned int)s) << 16;
  float f;
  __builtin_memcpy(&f, &x, 4);
  return f;
}

// async global->LDS, 16B per lane, wave-uniform LDS base
__device__ __forceinline__ void gl_lds16(const unsigned short* gsrc, unsigned short* ldst) {
  __builtin_amdgcn_global_load_lds(
      (const __attribute__((address_space(1))) void*)gsrc,
      (__attribute__((address_space(3))) void*)ldst, 16, 0, 0);
}

// ---------- f32 -> bf16 convert, float4-vectorized ----------
__global__ __launch_bounds__(256) void conv_kernel(const float4* __restrict__ in,
                                                   ushort4* __restrict__ out, int n4) {
  int stride = gridDim.x * blockDim.x;
  for (int i = blockIdx.x * blockDim.x + threadIdx.x; i < n4; i += stride) {
    float4 v = in[i];
    ushort4 o;
    o.x = f2bf(v.x); o.y = f2bf(v.y); o.z = f2bf(v.z); o.w = f2bf(v.w);
    out[i] = o;
  }
}

// ---------- 256x256-tile bf16 NT GEMM, 8-phase-style schedule ----------
// out[m][n] = sum_k A[m][k]*Bm[n][k], K=1024 fixed. 8 waves (2Mx4N), BK=64,
// LDS 128KB double-buffered, XOR-swizzled (byte ^= (row&7)<<4) both sides,
// counted vmcnt(8) per K-tile (staging 1 tile ahead, next tile in flight).
// MODE 0 (N=2048 stacked): n<1024 -> alpha=sigmoid(acc+bias0[n]) fp32
//                          n>=1024 -> out1b = bf16(acc + bias1[n-1024])
// MODE 1 (N=1024): out0[idx] = acc + bias0[n]*bias1[idx]  (y = hs C^T + D*u)
template <int MODE>
__global__ __launch_bounds__(512, 2) void gemm256(const unsigned short* __restrict__ A,
                                                  const unsigned short* __restrict__ Bm,
                                                  const float* __restrict__ bias0,
                                                  const float* __restrict__ bias1,
                                                  float* __restrict__ out0,
                                                  unsigned short* __restrict__ out1b,
                                                  int nbn) {
  constexpr int K = 1024;
  constexpr int NT = 16;                 // K / 64
  __shared__ __align__(16) unsigned short lds[2][32768];  // [buf][ A:16384 | B:16384 ]

  const int tid = threadIdx.x;
  const int lane = tid & 63, wave = tid >> 6;
  const int wr = wave >> 2, wc = wave & 3;          // 2 x 4 wave grid
  const int l15 = lane & 15, lhi = lane >> 4;

  // bijective XCD swizzle (nwg % 8 == 0 for both grids)
  const int cpx = gridDim.x >> 3;
  const int swz = (blockIdx.x & 7) * cpx + (blockIdx.x >> 3);
  const int m0 = (swz / nbn) * 256, n0 = (swz % nbn) * 256;

  // staging: thread covers row (chunk*64 + tid>>3), 16B slot pre-swizzled in GLOBAL col
  const int rsub = (tid >> 3) & 63;
  const int col16 = (((tid & 7) ^ ((tid >> 3) & 7)) << 3);   // element offset
  const unsigned short* gA = A + (size_t)(m0 + rsub) * K + col16;
  const unsigned short* gB = Bm + (size_t)(n0 + rsub) * K + col16;
  const int ldsw = wave * 512;           // wave-uniform ushort offset within 64-row chunk

  // ds_read byte offsets: addr = row*128 + ((kk*64 + lhi*16) ^ ((row&7)<<4)); row&7 == l15&7
  const int swzr = (l15 & 7) << 4;
  const int aoff0 = (wr * 128 + l15) * 128 + ((lhi * 16) ^ swzr);
  const int aoff1 = (wr * 128 + l15) * 128 + ((64 + lhi * 16) ^ swzr);
  const int boff0 = (wc * 64 + l15) * 128 + ((lhi * 16) ^ swzr);
  const int boff1 = (wc * 64 + l15) * 128 + ((64 + lhi * 16) ^ swzr);

  f32x4 acc[8][4] = {};

  auto stage = [&](int t) {
    unsigned short* dst = &lds[t & 1][0];
#pragma unroll
    for (int c = 0; c < 4; ++c)
      gl_lds16(gA + t * 64 + c * 64 * K, dst + c * 4096 + ldsw);
#pragma unroll
    for (int c = 0; c < 4; ++c)
      gl_lds16(gB + t * 64 + c * 64 * K, dst + 16384 + c * 4096 + ldsw);
  };

  stage(0);
  WAITV(0);
  BAR();
  stage(1);                              // tile1 in flight across iteration 0

  for (int t = 0; t < NT; ++t) {
    const char* sAb = (const char*)&lds[t & 1][0];
    const char* sBb = sAb + 32768;
    bf16x8 af[4][2], bl[2][2], bh[2][2];

    // ---- phase 0: A rows 0..63 + B cols 0..31; MFMA q(0,0) ----
#pragma unroll
    for (int i = 0; i < 4; ++i) {
      af[i][0] = *(const bf16x8*)(sAb + aoff0 + i * 2048);
      af[i][1] = *(const bf16x8*)(sAb + aoff1 + i * 2048);
    }
#pragma unroll
    for (int j = 0; j < 2; ++j) {
      bl[j][0] = *(const bf16x8*)(sBb + boff0 + j * 2048);
      bl[j][1] = *(const bf16x8*)(sBb + boff1 + j * 2048);
    }
    __builtin_amdgcn_s_setprio(1);
#pragma unroll
    for (int i = 0; i < 4; ++i)
#pragma unroll
      for (int j = 0; j < 2; ++j) {
        acc[i][j] = __builtin_amdgcn_mfma_f32_16x16x32_bf16(af[i][0], bl[j][0], acc[i][j], 0, 0, 0);
        acc[i][j] = __builtin_amdgcn_mfma_f32_16x16x32_bf16(af[i][1], bl[j][1], acc[i][j], 0, 0, 0);
      }
    __builtin_amdgcn_s_setprio(0);
    BAR();

    // ---- phase 1: B cols 32..63; MFMA q(0,1) (reuse af) ----
#pragma unroll
    for (int j = 0; j < 2; ++j) {
      bh[j][0] = *(const bf16x8*)(sBb + boff0 + (j + 2) * 2048);
      bh[j][1] = *(const bf16x8*)(sBb + boff1 + (j + 2) * 2048);
    }
    __builtin_amdgcn_s_setprio(1);
#pragma unroll
    for (int i = 0; i < 4; ++i)
#pragma unroll
      for (int j = 0; j < 2; ++j) {
        acc[i][j + 2] = __builtin_amdgcn_mfma_f32_16x16x32_bf16(af[i][0], bh[j][0], acc[i][j + 2], 0, 0, 0);
        acc[i][j + 2] = __builtin_amdgcn_mfma_f32_16x16x32_bf16(af[i][1], bh[j][1], acc[i][j + 2], 0, 0, 0);
      }
    __builtin_amdgcn_s_setprio(0);
    BAR();

    // ---- phase 2: A rows 64..127; MFMA q(1,0) (reuse bl) ----
#pragma unroll
    for (int i = 0; i < 4; ++i) {
      af[i][0] = *(const bf16x8*)(sAb + aoff0 + (i + 4) * 2048);
      af[i][1] = *(const bf16x8*)(sAb + aoff1 + (i + 4) * 2048);
    }
    __builtin_amdgcn_s_setprio(1);
#pragma unroll
    for (int i = 0; i < 4; ++i)
#pragma unroll
      for (int j = 0; j < 2; ++j) {
        acc[i + 4][j] = __builtin_amdgcn_mfma_f32_16x16x32_bf16(af[i][0], bl[j][0], acc[i + 4][j], 0, 0, 0);
        acc[i + 4][j] = __builtin_amdgcn_mfma_f32_16x16x32_bf16(af[i][1], bl[j][1], acc[i + 4][j], 0, 0, 0);
      }
    __builtin_amdgcn_s_setprio(0);
    BAR();

    // ---- phase 3: MFMA q(1,1) (reuse af + bh, no ds_reads) ----
    __builtin_amdgcn_s_setprio(1);
#pragma unroll
    for (int i = 0; i < 4; ++i)
#pragma unroll
      for (int j = 0; j < 2; ++j) {
        acc[i + 4][j + 2] = __builtin_amdgcn_mfma_f32_16x16x32_bf16(af[i][0], bh[j][0], acc[i + 4][j + 2], 0, 0, 0);
        acc[i + 4][j + 2] = __builtin_amdgcn_mfma_f32_16x16x32_bf16(af[i][1], bh[j][1], acc[i + 4][j + 2], 0, 0, 0);
      }
    __builtin_amdgcn_s_setprio(0);

    // ---- tail: re-stage freed buffer, publish tile t+1, keep t+2 in flight ----
    if (t + 1 < NT) {
      BAR();                              // all waves done reading buf[t&1]
      if (t + 2 < NT) {
        stage(t + 2);                     // 8 loads into buf[t&1]
        WAITV(8);                         // tile t+1 landed; t+2 stays in flight
      } else {
        WAITV(0);                         // only tile t+1 outstanding
      }
      BAR();                              // all waves observed tile t+1
    }
  }

  // ---- epilogue ----
  const int gcolb = n0 + wc * 64 + l15;
  const int growb = m0 + wr * 128 + lhi * 4;
  if (MODE == 0) {
    if (n0 < 1024) {
#pragma unroll
      for (int j = 0; j < 4; ++j) {
        const int gcol = gcolb + j * 16;
        const float b0 = bias0[gcol];
#pragma unroll
        for (int i = 0; i < 8; ++i)
#pragma unroll
          for (int r = 0; r < 4; ++r) {
            float z = acc[i][j][r] + b0;
            out0[(size_t)(growb + i * 16 + r) * 1024 + gcol] = 1.0f / (1.0f + __expf(-z));
          }
      }
    } else {
#pragma unroll
      for (int j = 0; j < 4; ++j) {
        const int c = gcolb + j * 16 - 1024;
        const float b1 = bias1[c];
#pragma unroll
        for (int i = 0; i < 8; ++i)
#pragma unroll
          for (int r = 0; r < 4; ++r)
            out1b[(size_t)(growb + i * 16 + r) * 1024 + c] = f2bf(acc[i][j][r] + b1);
      }
    }
  } else {
#pragma unroll
    for (int j = 0; j < 4; ++j) {
      const int gcol = gcolb + j * 16;
      const float dv = bias0[gcol];
#pragma unroll
      for (int i = 0; i < 8; ++i)
#pragma unroll
        for (int r = 0; r < 4; ++r) {
          size_t idx = (size_t)(growb + i * 16 + r) * 1024 + gcol;
          out0[idx] = acc[i][j][r] + dv * bias1[idx];
        }
    }
  }
}

// ---------- chunked scan, pass 1: per-chunk (P = prod a, S = local scan end) ----------
__global__ __launch_bounds__(256) void scan_stats(const float* __restrict__ alpha,
                                                  const unsigned short* __restrict__ Bu,
                                                  float* __restrict__ P,
                                                  float* __restrict__ S) {
  int b = blockIdx.x >> 6;
  int c = (blockIdx.x >> 2) & 15;
  int n = ((blockIdx.x & 3) << 8) | threadIdx.x;
  int bn = (b << 10) | n;
  size_t base = ((size_t)b * 2048 + c * 128) * 1024 + n;
  float h = 0.0f, p = 1.0f;
  for (int t = 0; t < 128; t += 8) {
    float a[8], bb[8];
#pragma unroll
    for (int q = 0; q < 8; ++q) {
      size_t idx = base + (size_t)(t + q) * 1024;
      a[q] = alpha[idx];
      bb[q] = bf2f(Bu[idx]);
    }
#pragma unroll
    for (int q = 0; q < 8; ++q) {
      h = __builtin_fmaf(a[q], h, bb[q]);
      p *= a[q];
    }
  }
  P[c * 8192 + bn] = p;
  S[c * 8192 + bn] = h;
}

// ---------- chunked scan, pass 2: compose carry-in, recompute, emit hs bf16 ----------
__global__ __launch_bounds__(256) void scan_apply(const float* __restrict__ alpha,
                                                  const unsigned short* __restrict__ Bu,
                                                  const float* __restrict__ P,
                                                  const float* __restrict__ S,
                                                  unsigned short* __restrict__ hs) {
  int b = blockIdx.x >> 6;
  int c = (blockIdx.x >> 2) & 15;
  int n = ((blockIdx.x & 3) << 8) | threadIdx.x;
  int bn = (b << 10) | n;
  size_t base = ((size_t)b * 2048 + c * 128) * 1024 + n;
  float h = 0.0f;
  for (int j = 0; j < c; ++j) h = S[j * 8192 + bn] + P[j * 8192 + bn] * h;
  for (int t = 0; t < 128; t += 8) {
    float a[8], bb[8];
#pragma unroll
    for (int q = 0; q < 8; ++q) {
      size_t idx = base + (size_t)(t + q) * 1024;
      a[q] = alpha[idx];
      bb[q] = bf2f(Bu[idx]);
    }
#pragma unroll
    for (int q = 0; q < 8; ++q) {
      h = __builtin_fmaf(a[q], h, bb[q]);
      hs[base + (size_t)(t + q) * 1024] = f2bf(h);
    }
  }
}

extern "C" void kernel_launch(void* const* d_in, const int* in_sizes, int n_in,
                              void* d_out, int out_size, void* d_ws, size_t ws_size,
                              hipStream_t stream) {
  const float* u   = (const float*)d_in[0];
  const float* Waw = (const float*)d_in[1];
  const float* Wab = (const float*)d_in[2];
  const float* WBw = (const float*)d_in[3];
  const float* WBb = (const float*)d_in[4];
  const float* Cw  = (const float*)d_in[5];
  const float* Dv  = (const float*)d_in[6];
  float* y = (float*)d_out;

  const int DM = 1024, NS = 1024;
  const size_t M = 16384;  // B*T

  // Workspace map (verified non-overlapping, round 3):
  //   u_bf  [  0, 32)MB   W_bf [32,36)MB   C_bf [36,38)MB
  //   alpha [ 38,102)MB   Bu_bf[102,134)MB hs   [134,166)MB
  //   Pc    [166,...)     Sc   [167,...)
  char* ws = (char*)d_ws;
  unsigned short* u_bf  = (unsigned short*)(ws);
  unsigned short* W_bf  = (unsigned short*)(ws + (32ull << 20));
  unsigned short* C_bf  = (unsigned short*)(ws + (36ull << 20));
  float*          alpha = (float*)(ws + (38ull << 20));
  unsigned short* Bu_bf = (unsigned short*)(ws + (102ull << 20));
  unsigned short* hs    = (unsigned short*)(ws + (134ull << 20));
  float*          Pc    = (float*)(ws + (166ull << 20));
  float*          Sc    = (float*)(ws + (167ull << 20));

  conv_kernel<<<2048, 256, 0, stream>>>((const float4*)u, (ushort4*)u_bf, (int)(M * DM / 4));
  conv_kernel<<<512, 256, 0, stream>>>((const float4*)Waw, (ushort4*)W_bf, NS * DM / 4);
  conv_kernel<<<512, 256, 0, stream>>>((const float4*)WBw, (ushort4*)(W_bf + (size_t)NS * DM),
                                       NS * DM / 4);
  conv_kernel<<<512, 256, 0, stream>>>((const float4*)Cw, (ushort4*)C_bf, NS * DM / 4);

  // GEMM1: [M,2048] = u @ [W_alpha;W_B]^T  (grid 64x8 = 512 blocks, nbn=8)
  gemm256<0><<<512, 512, 0, stream>>>(u_bf, W_bf, Wab, WBb, alpha, Bu_bf, 8);
  // scan
  scan_stats<<<512, 256, 0, stream>>>(alpha, Bu_bf, Pc, Sc);
  scan_apply<<<512, 256, 0, stream>>>(alpha, Bu_bf, Pc, Sc, hs);
  // GEMM3: y = hs @ C^T + D*u  (grid 64x4 = 256 blocks, nbn=4)
  gemm256<1><<<256, 512, 0, stream>>>(hs, C_bf, Dv, u, y, nullptr, 4);
}